// Round 12
// baseline (430.973 us; speedup 1.0000x reference)
//
#include <hip/hip_runtime.h>
#include <hip/hip_bf16.h>

// DGCF forward, MI355X. f32 in/out.
// R12: scores+softmax+rowsum fused back into k_iter in the q/l lane layout:
// fn stays in registers (no fnb round-trip, no csr_head, no fn[head] gather),
// dot reduce = xor1+xor2 per 4 edges, softmax den = xor4+xor8, rowsum in regs
// (xor16/32 at row end) -> d4n. k_scores_edge / k_dinv2 / k_headfill deleted.
#define NUSER 50000
#define NITEM 50000
#define NN    100000          // NUSER+NITEM
#define NNZ_  1000000
#define DIM_  64
#define NBLK  391             // ceil_div(NN,256) == bucket count
#define EPB   2560            // edges per bin-pass block (391*2560 >= NNZ)

#define FL_SVC    1   // svals == 0.25 (iteration 0 walk1)
#define FL_SCORES 2   // walk2: scores + A-update + softmax + rowsum -> d4n
#define FL_OUT    4   // out += fn
#define FL_NEXT   8   // write ego_next / te_next
#define FL_FIN    16  // out = (out + fn) / 3
#define FL_ACONST 32  // walk2: A_old == 1
#define FL_ASTORE 64  // walk2: store A_new

static inline int ceil_div(int a, int b) { return (a + b - 1) / b; }

static __device__ inline float bf2f(unsigned short u) {
    return __uint_as_float(((unsigned int)u) << 16);
}
static __device__ inline unsigned short f2bf(float f) {
    unsigned int x = __float_as_uint(f);
    x += 0x7fffu + ((x >> 16) & 1u);
    return (unsigned short)(x >> 16);
}

// ego = concat(user,item) bf16; te = tanh(l2norm chunk16) bf16; out = ego f32.
__global__ void k_init(const float* __restrict__ eu, const float* __restrict__ ei,
                       unsigned short* __restrict__ ego, unsigned short* __restrict__ te,
                       float* __restrict__ out) {
    int i = blockIdx.x * 256 + threadIdx.x;
    if (i >= NN * DIM_) return;
    float v = (i < NUSER * DIM_) ? eu[i] : ei[i - NUSER * DIM_];
    out[i] = v;
    ego[i] = f2bf(v);
    float s = v * v;
    s += __shfl_xor(s, 1); s += __shfl_xor(s, 2);
    s += __shfl_xor(s, 4); s += __shfl_xor(s, 8);
    float nrm = v / fmaxf(sqrtf(s), 1e-12f);
    float ex = __expf(2.0f * nrm);
    te[i] = f2bf((ex - 1.0f) / (ex + 1.0f));
}

// ---- bucketed CSR build (once per launch) ----
__global__ void k_bcount(const int* __restrict__ head, int* __restrict__ bcount) {
    __shared__ int cnt[NBLK];
    int tid = threadIdx.x;
    for (int i = tid; i < NBLK; i += 256) cnt[i] = 0;
    __syncthreads();
    int e0 = blockIdx.x * EPB;
    int e1 = min(e0 + EPB, NNZ_);
    for (int e = e0 + tid; e < e1; e += 256)
        atomicAdd(&cnt[head[e] >> 8], 1);
    __syncthreads();
    for (int i = tid; i < NBLK; i += 256)
        if (cnt[i]) atomicAdd(&bcount[i], cnt[i]);
}

__global__ void k_bscan(const int* __restrict__ bcount, int* __restrict__ bucket_base,
                        int* __restrict__ bucket_cursor, int* __restrict__ row_start_end) {
    __shared__ int sh[512];
    int t = threadIdx.x;
    int v = (t < NBLK) ? bcount[t] : 0;
    sh[t] = v;
    __syncthreads();
    for (int off = 1; off < 512; off <<= 1) {
        int u = 0;
        if (t >= off) u = sh[t - off];
        __syncthreads();
        sh[t] += u;
        __syncthreads();
    }
    if (t < NBLK) {
        int base = sh[t] - v;
        bucket_base[t] = base;
        bucket_cursor[t] = base;
    }
    if (t == 511) {
        bucket_base[NBLK] = sh[511];    // == NNZ_
        row_start_end[0] = sh[511];
    }
}

__global__ void k_binscat(const int* __restrict__ head, const int* __restrict__ tail,
                          int* __restrict__ bucket_cursor, int2* __restrict__ bin) {
    __shared__ int cnt[NBLK];
    __shared__ int chunk[NBLK];
    int tid = threadIdx.x;
    for (int i = tid; i < NBLK; i += 256) cnt[i] = 0;
    __syncthreads();
    int e0 = blockIdx.x * EPB;
    int e1 = min(e0 + EPB, NNZ_);
    for (int e = e0 + tid; e < e1; e += 256)
        atomicAdd(&cnt[head[e] >> 8], 1);
    __syncthreads();
    for (int i = tid; i < NBLK; i += 256) {
        chunk[i] = cnt[i] ? atomicAdd(&bucket_cursor[i], cnt[i]) : 0;
        cnt[i] = 0;   // reuse as local cursor
    }
    __syncthreads();
    for (int e = e0 + tid; e < e1; e += 256) {
        int h = head[e], t = tail[e];
        int b = h >> 8;
        int off = atomicAdd(&cnt[b], 1);
        bin[chunk[b] + off] = make_int2(h, t);
    }
}

__global__ void k_bucket(const int2* __restrict__ bin, const int* __restrict__ bucket_base,
                         int* __restrict__ row_start, float4* __restrict__ d4a,
                         int* __restrict__ csr_tail) {
    __shared__ int deg[256];
    __shared__ int sh[256];
    __shared__ int cur[256];
    int tid = threadIdx.x;
    int b = blockIdx.x;
    int n0 = b << 8;
    int e0 = bucket_base[b], e1 = bucket_base[b + 1];
    deg[tid] = 0;
    __syncthreads();
    for (int e = e0 + tid; e < e1; e += 256)
        atomicAdd(&deg[bin[e].x - n0], 1);
    __syncthreads();
    int myDeg = deg[tid];
    sh[tid] = myDeg;
    __syncthreads();
    for (int off = 1; off < 256; off <<= 1) {
        int u = 0;
        if (tid >= off) u = sh[tid - off];
        __syncthreads();
        sh[tid] += u;
        __syncthreads();
    }
    int loff = sh[tid] - myDeg;
    int n = n0 + tid;
    if (n < NN) {
        row_start[n] = e0 + loff;
        float dd = (myDeg > 0) ? 2.0f / sqrtf((float)myDeg) : 0.0f;
        d4a[n] = make_float4(dd, dd, dd, dd);
    }
    cur[tid] = e0 + loff;
    __syncthreads();
    for (int e = e0 + tid; e < e1; e += 256) {
        int2 p = bin[e];
        int pos = atomicAdd(&cur[p.x - n0], 1);
        csr_tail[pos] = p.y;
    }
}

// ---- per-iteration mega-kernel: one wave per node, 4 edges per step ----
// lane = 16*q + l: q = edge slot (0..3), l = dim quad (dims 4l..4l+3), f = l>>2.
template<int FLAGS>
__global__ void k_iter(unsigned short* __restrict__ svals,        // bf16 [NNZ*4] CSR (rw)
                       const float* __restrict__ d4c,             // f32 [NN*4] cur
                       float* __restrict__ d4n,                   // f32 [NN*4] next
                       const unsigned short* __restrict__ ego,    // bf16 [NN*64]
                       const unsigned short* __restrict__ te,     // bf16 [NN*64]
                       const int* __restrict__ row_start, const int* __restrict__ csr_tail,
                       float* __restrict__ A4,                    // f32 [NNZ*4] CSR
                       float* __restrict__ out,
                       unsigned short* __restrict__ egon, unsigned short* __restrict__ ten) {
    int n = (blockIdx.x * 256 + threadIdx.x) >> 6;
    if (n >= NN) return;
    int lane = threadIdx.x & 63;
    int q = lane >> 4;
    int l = lane & 15;
    int f = l >> 2;
    int r0 = __builtin_amdgcn_readfirstlane(row_start[n]);
    int r1 = __builtin_amdgcn_readfirstlane(row_start[n + 1]);

    // ---- walk1 ----
    float ax = 0.f, ay = 0.f, az = 0.f, aw = 0.f;
    int kb = r0;
    for (; kb + 7 < r1; kb += 8) {
        int i0 = kb + q, i1 = kb + 4 + q;
        int t0 = csr_tail[i0], t1 = csr_tail[i1];
        float w0, w1;
        if (FLAGS & FL_SVC) { w0 = 0.25f; w1 = 0.25f; }
        else { w0 = bf2f(svals[i0 * 4 + f]); w1 = bf2f(svals[i1 * 4 + f]); }
        w0 *= d4c[t0 * 4 + f]; w1 *= d4c[t1 * 4 + f];
        ushort4 u0 = *(const ushort4*)(ego + (size_t)t0 * 64 + 4 * l);
        ushort4 u1 = *(const ushort4*)(ego + (size_t)t1 * 64 + 4 * l);
        ax += w0 * bf2f(u0.x) + w1 * bf2f(u1.x);
        ay += w0 * bf2f(u0.y) + w1 * bf2f(u1.y);
        az += w0 * bf2f(u0.z) + w1 * bf2f(u1.z);
        aw += w0 * bf2f(u0.w) + w1 * bf2f(u1.w);
    }
    for (; kb < r1; kb += 4) {
        int i0 = kb + q;
        bool v = (i0 < r1);
        int ic = v ? i0 : r0;
        int t0 = csr_tail[ic];
        float w0 = (FLAGS & FL_SVC) ? 0.25f : bf2f(svals[ic * 4 + f]);
        w0 *= d4c[t0 * 4 + f];
        w0 = v ? w0 : 0.0f;
        ushort4 u0 = *(const ushort4*)(ego + (size_t)t0 * 64 + 4 * l);
        ax += w0 * bf2f(u0.x); ay += w0 * bf2f(u0.y);
        az += w0 * bf2f(u0.z); aw += w0 * bf2f(u0.w);
    }

    ax += __shfl_xor(ax, 16); ax += __shfl_xor(ax, 32);
    ay += __shfl_xor(ay, 16); ay += __shfl_xor(ay, 32);
    az += __shfl_xor(az, 16); az += __shfl_xor(az, 32);
    aw += __shfl_xor(aw, 16); aw += __shfl_xor(aw, 32);
    float s = ax * ax + ay * ay + az * az + aw * aw;
    s += __shfl_xor(s, 1); s += __shfl_xor(s, 2);
    float inv = 1.0f / fmaxf(sqrtf(s), 1e-12f);
    float fx = ax * inv, fy = ay * inv, fz = az * inv, fw = aw * inv;

    // ---- epilogues (q==0 lanes, coalesced x4) ----
    if (q == 0) {
        if (FLAGS & FL_FIN) {
            float4* po = (float4*)(out + (size_t)n * 64 + 4 * l);
            float4 ov = *po;
            ov.x = (ov.x + fx) * (1.0f / 3.0f); ov.y = (ov.y + fy) * (1.0f / 3.0f);
            ov.z = (ov.z + fz) * (1.0f / 3.0f); ov.w = (ov.w + fw) * (1.0f / 3.0f);
            *po = ov;
        } else if (FLAGS & FL_OUT) {
            float4* po = (float4*)(out + (size_t)n * 64 + 4 * l);
            float4 ov = *po;
            ov.x += fx; ov.y += fy; ov.z += fz; ov.w += fw;
            *po = ov;
        }
        if (FLAGS & FL_NEXT) {
            ushort4 o; o.x = f2bf(fx); o.y = f2bf(fy); o.z = f2bf(fz); o.w = f2bf(fw);
            *(ushort4*)(egon + (size_t)n * 64 + 4 * l) = o;
            float e0 = __expf(2.0f * fx), e1 = __expf(2.0f * fy);
            float e2 = __expf(2.0f * fz), e3 = __expf(2.0f * fw);
            ushort4 p;
            p.x = f2bf((e0 - 1.0f) / (e0 + 1.0f)); p.y = f2bf((e1 - 1.0f) / (e1 + 1.0f));
            p.z = f2bf((e2 - 1.0f) / (e2 + 1.0f)); p.w = f2bf((e3 - 1.0f) / (e3 + 1.0f));
            *(ushort4*)(ten + (size_t)n * 64 + 4 * l) = p;
        }
    }

    // ---- walk2: scores + A-update + softmax + rowsum (fn in registers) ----
    if (FLAGS & FL_SCORES) {
        float rs = 0.0f;
        bool wl = ((l & 3) == 0);
        int kb2 = r0;
        for (; kb2 + 3 < r1; kb2 += 4) {
            int i = kb2 + q;
            int t = csr_tail[i];
            ushort4 u = *(const ushort4*)(te + (size_t)t * 64 + 4 * l);
            float p = fx * bf2f(u.x) + fy * bf2f(u.y) + fz * bf2f(u.z) + fw * bf2f(u.w);
            p += __shfl_xor(p, 1); p += __shfl_xor(p, 2);   // sum dim-quads -> p_f
            float a = (FLAGS & FL_ACONST) ? 1.0f : A4[i * 4 + f];
            a += p;
            if ((FLAGS & FL_ASTORE) && wl) A4[i * 4 + f] = a;
            float e = __expf(a);
            float den = e;
            den += __shfl_xor(den, 4); den += __shfl_xor(den, 8);  // sum factors
            float sv = e / den;
            rs += sv;
            if (wl) svals[i * 4 + f] = f2bf(sv);
        }
        for (; kb2 < r1; kb2 += 4) {
            int i = kb2 + q;
            bool v = (i < r1);
            int ic = v ? i : r0;
            int t = csr_tail[ic];
            ushort4 u = *(const ushort4*)(te + (size_t)t * 64 + 4 * l);
            float p = fx * bf2f(u.x) + fy * bf2f(u.y) + fz * bf2f(u.z) + fw * bf2f(u.w);
            p += __shfl_xor(p, 1); p += __shfl_xor(p, 2);
            float a = (FLAGS & FL_ACONST) ? 1.0f : A4[ic * 4 + f];
            a += p;
            if ((FLAGS & FL_ASTORE) && wl && v) A4[i * 4 + f] = a;
            float e = __expf(a);
            float den = e;
            den += __shfl_xor(den, 4); den += __shfl_xor(den, 8);
            float sv = e / den;
            if (v) {
                rs += sv;
                if (wl) svals[i * 4 + f] = f2bf(sv);
            }
        }
        // rs: per-lane sum over its slot's edges (x4 replicated across l&3) ->
        // reduce over slots only; lanes within l-quad already identical.
        rs += __shfl_xor(rs, 16); rs += __shfl_xor(rs, 32);
        if (q == 0 && wl)
            d4n[n * 4 + f] = (rs > 0.0f) ? 1.0f / sqrtf(fmaxf(rs, 1e-12f)) : 0.0f;
    }
}

extern "C" void kernel_launch(void* const* d_in, const int* in_sizes, int n_in,
                              void* d_out, int out_size, void* d_ws, size_t ws_size,
                              hipStream_t stream) {
    const float* eu = (const float*)d_in[0];
    const float* ei = (const float*)d_in[1];
    const int* head = (const int*)d_in[2];
    const int* tail = (const int*)d_in[3];
    float* out = (float*)d_out;   // 3-term accumulator, scaled at it3 (FL_FIN)

    // workspace layout — ~90 MB (16B-aligned first)
    float* A4 = (float*)d_ws;                               // 16 MB
    float* d4a = A4 + (size_t)NNZ_ * 4;                     // 1.6 MB
    float* d4b = d4a + (size_t)NN * 4;                      // 1.6 MB
    unsigned short* svals = (unsigned short*)(d4b + (size_t)NN * 4);  // 8 MB
    unsigned short* ego_a = svals + (size_t)NNZ_ * 4;       // 12.8 MB
    unsigned short* te_a  = ego_a + (size_t)NN * DIM_;      // 12.8 MB
    unsigned short* ego_b = te_a + (size_t)NN * DIM_;       // 12.8 MB
    unsigned short* te_b  = ego_b + (size_t)NN * DIM_;      // 12.8 MB
    int2* bin = (int2*)(te_b + (size_t)NN * DIM_);          // 8 MB
    int* csr_tail = (int*)(bin + NNZ_);                     // 4 MB
    int* row_start = csr_tail + NNZ_;                       // NN+1
    int* bcount = row_start + (NN + 1);                     // NBLK
    int* bucket_base = bcount + NBLK;                       // NBLK+1
    int* bucket_cursor = bucket_base + (NBLK + 1);          // NBLK

    const int node_blocks = ceil_div(NN * DIM_, 256);      // 25000
    const int wave_blocks = ceil_div(NN * 64, 256);        // 25000

    k_init<<<node_blocks, 256, 0, stream>>>(eu, ei, ego_a, te_a, out);

    // bucketed CSR build + d4_0 seed
    hipMemsetAsync(bcount, 0, NBLK * sizeof(int), stream);
    k_bcount<<<NBLK, 256, 0, stream>>>(head, bcount);
    k_bscan<<<1, 512, 0, stream>>>(bcount, bucket_base, bucket_cursor, &row_start[NN]);
    k_binscat<<<NBLK, 256, 0, stream>>>(head, tail, bucket_cursor, bin);
    k_bucket<<<NBLK, 256, 0, stream>>>(bin, bucket_base, row_start, (float4*)d4a, csr_tail);

    // it0 = (0,0): walk1 svals==0.25; walk2: A_old==1, store A_1 -> svals_1, d4_1(b)
    k_iter<FL_SVC | FL_SCORES | FL_ACONST | FL_ASTORE><<<wave_blocks, 256, 0, stream>>>(
        svals, d4a, d4b, ego_a, te_a, row_start, csr_tail, A4, out, ego_b, te_b);
    // it1 = (0,1): layer-0 out + next ego/te; walk2: RMW A_2 -> svals_2, d4_2(a)
    k_iter<FL_SCORES | FL_ASTORE | FL_OUT | FL_NEXT><<<wave_blocks, 256, 0, stream>>>(
        svals, d4b, d4a, ego_a, te_a, row_start, csr_tail, A4, out, ego_b, te_b);
    // it2 = (1,0): walk2 reads A_2; A_3 store dead -> svals_3, d4_3(b)
    k_iter<FL_SCORES><<<wave_blocks, 256, 0, stream>>>(
        svals, d4a, d4b, ego_b, te_b, row_start, csr_tail, A4, out, ego_a, te_a);
    // it3 = (1,1): walk1 only; final out = (out + fn) / 3
    k_iter<FL_OUT | FL_FIN><<<wave_blocks, 256, 0, stream>>>(
        svals, d4b, d4a, ego_b, te_b, row_start, csr_tail, A4, out, ego_a, te_a);
}